// Round 8
// baseline (252.951 us; speedup 1.0000x reference)
//
#include <hip/hip_runtime.h>
#include <hip/hip_bf16.h>
#include <stdint.h>

// ---------- types ----------
typedef __bf16 bf16x8 __attribute__((ext_vector_type(8)));
typedef float  f32x4  __attribute__((ext_vector_type(4)));
typedef unsigned int u32x4 __attribute__((ext_vector_type(4)));

__device__ __forceinline__ unsigned short f2bf(float x) {
    union { float f; unsigned u; } v; v.f = x;
    unsigned r = v.u + 0x7fffu + ((v.u >> 16) & 1u);   // RNE
    return (unsigned short)(r >> 16);
}

__device__ __forceinline__ void async16(const void* g, void* l) {
    __builtin_amdgcn_global_load_lds(
        (const __attribute__((address_space(1))) void*)g,
        (__attribute__((address_space(3))) void*)l,
        16, 0, 0);
}

// ---------- bf16 B^T GEMM, 128x128 tile, BK=32, 4 waves, DOUBLE-BUFFERED ----------
// A: M x K (row-major bf16 bits, lda), Bt: N x K (row-major, ldb)
// C[m][n] = scale * sum_k A[m][k] * Bt[n][k]
// VFOLD: tiles with n0 >= nsplit stored TRANSPOSED to VtOut direct from acc.
// SPLITK (PV only; 16 row-blocks, split at k=1024): gridDim.y = 24.
//   y in [0,8):  chunk1, bm=15-y, k in [1024,(bm+1)*128) -> Part1
//   y in [8,24): chunk0, bm=23-y, k in [0,min(1024,(bm+1)*128))
//                -> rows<1024 direct to C; rows>=1024 to Part0
//   d_out is NEVER read by any kernel (merge is a pure write) — graph-replay safe.
template <typename OutT, bool CAUSAL_SKIP, bool VFOLD, bool SPLITK>
__global__ __launch_bounds__(256, 3) void gemm_bt(
    const unsigned short* __restrict__ A,
    const unsigned short* __restrict__ Bt,
    OutT* __restrict__ C,
    unsigned short* __restrict__ VtOut,
    float* __restrict__ Part0,
    float* __restrict__ Part1,
    int M, int N, int K, int lda, int ldb, int ldc,
    int ldvt, int nsplit,
    long long sA, long long sB, long long sC, long long sVt, long long sPart,
    float scale)
{
    const int bn = blockIdx.x, bz = blockIdx.z;

    int bm, kbeg, kend;
    bool part = false;
    if constexpr (SPLITK) {
        const int y = blockIdx.y;
        if (y < 8) { bm = 15 - y; part = true;  kbeg = 1024; kend = (bm + 1) * 128; }
        else       { bm = 23 - y; part = false; kbeg = 0;    kend = min(1024, (bm + 1) * 128); }
    } else {
        bm = blockIdx.y; kbeg = 0; kend = K;
    }
    if (CAUSAL_SKIP && bn > bm) return;

    A  += (long long)bz * sA;
    Bt += (long long)bz * sB;
    C  += (long long)bz * sC;

    const int m0 = bm * 128, n0 = bn * 128;

    // [buf][A:128x32 | B:128x32], 16 KB per buffer
    __shared__ __align__(16) unsigned short LDS[2 * 2 * 128 * 32];

    const int tid  = threadIdx.x;
    const int w    = tid >> 6, l = tid & 63;
    const int wr   = w >> 1,  wc = w & 1;
    const int lrow = l & 15,  quad = l >> 4;

    f32x4 acc[4][4] = {};

    // staging: lane l of chunk c covers row 16c + (l>>2); physical k-slot l&3
    // holds logical chunk (l&3)^((l>>3)&3) (row-pair swizzle).
    const int rA0  = 32 * w + (l >> 2);
    const int cOff = (((l & 3) ^ ((l >> 3) & 3))) * 8;
    const unsigned short* aG0 = A  + (long long)(m0 + rA0)      * lda + cOff;
    const unsigned short* aG1 = A  + (long long)(m0 + rA0 + 16) * lda + cOff;
    const unsigned short* bG0 = Bt + (long long)(n0 + rA0)      * ldb + cOff;
    const unsigned short* bG1 = Bt + (long long)(n0 + rA0 + 16) * ldb + cOff;
    unsigned short* aL = &LDS[(2 * w) * 512 + l * 8];           // A region of buf0
    unsigned short* bL = aL + 4096;                             // B region of buf0

    const int sl = (lrow >> 1) & 3;   // un-swizzle for fragment reads

    // prologue: stage first tile into buf 0
    async16(aG0 + kbeg, aL);
    async16(aG1 + kbeg, aL + 512);
    async16(bG0 + kbeg, bL);
    async16(bG1 + kbeg, bL + 512);

    for (int k0 = kbeg; k0 < kend; k0 += 32) {
        const int cur = ((k0 >> 5) & 1) * 8192;   // element offset of current buf
        __syncthreads();                          // tile k0 ready in cur

        if (k0 + 32 < kend) {                     // prefetch next tile into other buf
            const int nxt = cur ^ 8192;
            async16(aG0 + k0 + 32, aL + nxt);
            async16(aG1 + k0 + 32, aL + nxt + 512);
            async16(bG0 + k0 + 32, bL + nxt);
            async16(bG1 + k0 + 32, bL + nxt + 512);
        }

        const unsigned short* As = &LDS[cur];
        const unsigned short* Bs = &LDS[cur + 4096];
        bf16x8 af[4], bfr[4];
#pragma unroll
        for (int i = 0; i < 4; i++) {
            af[i]  = *(const bf16x8*)&As[(wr * 64 + i * 16 + lrow) * 32 + (quad ^ sl) * 8];
            bfr[i] = *(const bf16x8*)&Bs[(wc * 64 + i * 16 + lrow) * 32 + (quad ^ sl) * 8];
        }
#pragma unroll
        for (int i = 0; i < 4; i++)
#pragma unroll
            for (int j = 0; j < 4; j++)
                acc[i][j] = __builtin_amdgcn_mfma_f32_16x16x32_bf16(af[i], bfr[j], acc[i][j], 0, 0, 0);
    }

    // ---- VFOLD: store this tile transposed, straight from acc ----
    if constexpr (VFOLD) {
        if (n0 >= nsplit) {
            unsigned short* Vp = VtOut + (long long)bz * sVt;
#pragma unroll
            for (int i = 0; i < 4; i++) {
                const int t = m0 + wr * 64 + i * 16 + quad * 4;
#pragma unroll
                for (int j = 0; j < 4; j++) {
                    const int d = (n0 - nsplit) + wc * 64 + j * 16 + lrow;
                    union { unsigned short u[4]; uint2 p; } o;
#pragma unroll
                    for (int r = 0; r < 4; r++) o.u[r] = f2bf(acc[i][j][r] * scale);
                    *(uint2*)(Vp + (long long)d * ldvt + t) = o.p;
                }
            }
            return;
        }
    }

    __syncthreads();   // all waves done before LDS is reused for repack

    // ---- epilogue: per-wave LDS repack (16 rows x 144 B stride, 2288 B/wave) ----
    char* eb = (char*)LDS + w * 2288;
    const int erow = l >> 2, ep = l & 3;

    if constexpr (sizeof(OutT) == 2) {
#pragma unroll
        for (int i = 0; i < 4; i++) {
#pragma unroll
            for (int j = 0; j < 4; j++)
#pragma unroll
                for (int r = 0; r < 4; r++)
                    *(unsigned short*)(eb + (quad * 4 + r) * 144 + (j * 16 + lrow) * 2) =
                        f2bf(acc[i][j][r] * scale);
            const long long gm = m0 + wr * 64 + i * 16 + erow;
#pragma unroll
            for (int c = 0; c < 2; c++) {
                u32x4 d = *(u32x4*)(eb + erow * 144 + ep * 32 + c * 16);
                *(u32x4*)((unsigned short*)C + gm * ldc + (n0 + wc * 64 + ep * 16 + c * 8)) = d;
            }
        }
    } else {
        float* fbase;
        if constexpr (SPLITK) {
            if (part)            fbase = Part1 + (long long)bz * sPart - (long long)1024 * ldc;
            else if (bm >= 8)    fbase = Part0 + (long long)bz * sPart - (long long)1024 * ldc;
            else                 fbase = (float*)C;
        } else {
            fbase = (float*)C;
        }
#pragma unroll
        for (int i = 0; i < 4; i++) {
            const long long gm = m0 + wr * 64 + i * 16 + erow;
#pragma unroll
            for (int jc = 0; jc < 2; jc++) {
#pragma unroll
                for (int jj = 0; jj < 2; jj++)
#pragma unroll
                    for (int r = 0; r < 4; r++)
                        *(float*)(eb + (quad * 4 + r) * 144 + (jj * 16 + lrow) * 4) =
                            acc[i][2 * jc + jj][r] * scale;
#pragma unroll
                for (int c = 0; c < 2; c++) {
                    f32x4 d = *(f32x4*)(eb + erow * 144 + ep * 32 + c * 16);
                    *(f32x4*)(fbase + gm * ldc + (n0 + wc * 64 + jc * 32 + ep * 8 + c * 4)) = d;
                }
            }
        }
    }
}

// ---------- out rows 1024..2047 = Part0 + Part1 (pure write, never reads out) ----------
__global__ __launch_bounds__(256) void merge_part(
    float* __restrict__ out, const float* __restrict__ p0, const float* __restrict__ p1)
{
    const int i = blockIdx.x * 256 + threadIdx.x;   // 0 .. 1048575
    const int bz = i >> 18;                          // 262144 float4 per batch-half
    const int r  = i & 262143;
    const float4* a4 = (const float4*)(p0 + (long long)bz * 1048576) + r;
    const float4* b4 = (const float4*)(p1 + (long long)bz * 1048576) + r;
    float4 a = *a4, b = *b4;
    a.x += b.x; a.y += b.y; a.z += b.z; a.w += b.w;
    *((float4*)(out + (long long)bz * 2097152 + 1048576) + r) = a;
}

// ---------- fp32 -> bf16 cast (vectorized) ----------
__global__ __launch_bounds__(256) void cast_f32_bf16(
    const float4* __restrict__ in, unsigned short* __restrict__ out, int n4)
{
    int i = blockIdx.x * 256 + threadIdx.x;
    if (i >= n4) return;
    float4 v = in[i];
    union { unsigned short u[4]; uint2 p; } o;
    o.u[0] = f2bf(v.x); o.u[1] = f2bf(v.y); o.u[2] = f2bf(v.z); o.u[3] = f2bf(v.w);
    *(uint2*)(out + (long long)i * 4) = o.p;
}

// ---------- fused W_{q,k,v} (1024x1024 fp32) -> concatenated W^T (3072 x 1024 bf16) ----------
__global__ __launch_bounds__(256) void transpose_cast_w3(
    const float* __restrict__ W0, const float* __restrict__ W1,
    const float* __restrict__ W2, unsigned short* __restrict__ out, int n)
{
    const float* in = (blockIdx.z == 0) ? W0 : (blockIdx.z == 1) ? W1 : W2;
    out += (long long)blockIdx.z * n * n;
    __shared__ float tile[32][33];
    const int tx = threadIdx.x, ty = threadIdx.y;
    const int c0 = blockIdx.x * 32, r0 = blockIdx.y * 32;
#pragma unroll
    for (int i = 0; i < 4; i++)
        tile[ty + i * 8][tx] = in[(long long)(r0 + ty + i * 8) * n + c0 + tx];
    __syncthreads();
#pragma unroll
    for (int i = 0; i < 4; i++)
        out[(long long)(c0 + ty + i * 8) * n + r0 + tx] = f2bf(tile[tx][ty + i * 8]);
}

// ---------- causal softmax: S (bf16, B*T rows of T) -> P (bf16), vectorized ----------
// Masked-out uint4 chunks skip the LOAD but still STORE zeros (P must be clean
// for the PV GEMM which reads the full K range).
__global__ __launch_bounds__(256) void causal_softmax_bf16(
    const unsigned short* __restrict__ S, unsigned short* __restrict__ P, int T)
{
    const int row = blockIdx.x;            // 0 .. B*T-1
    const int t   = row & (T - 1);
    const int L   = t + 1;
    const unsigned short* s = S + (long long)row * T;
    unsigned short* p = P + (long long)row * T;
    const int tid  = threadIdx.x;
    const int base = tid * 8;

    uint4 raw = (base < L) ? *(const uint4*)(s + base) : make_uint4(0, 0, 0, 0);
    unsigned rr[4] = {raw.x, raw.y, raw.z, raw.w};
    float v[8];
#pragma unroll
    for (int k = 0; k < 4; k++) {
        union { unsigned u; float f; } a, b;
        a.u = (rr[k] & 0xFFFFu) << 16;
        b.u = rr[k] & 0xFFFF0000u;
        v[2 * k] = a.f; v[2 * k + 1] = b.f;
    }
    float mx = -3.0e38f;
#pragma unroll
    for (int k = 0; k < 8; k++) {
        if (base + k >= L) v[k] = -3.0e38f;
        mx = fmaxf(mx, v[k]);
    }
#pragma unroll
    for (int off = 32; off; off >>= 1) mx = fmaxf(mx, __shfl_xor(mx, off));
    __shared__ float red[4], red2[4];
    const int wid = tid >> 6, lid = tid & 63;
    if (lid == 0) red[wid] = mx;
    __syncthreads();
    mx = fmaxf(fmaxf(red[0], red[1]), fmaxf(red[2], red[3]));

    float sum = 0.f;
#pragma unroll
    for (int k = 0; k < 8; k++) { v[k] = __expf(v[k] - mx); sum += v[k]; }
#pragma unroll
    for (int off = 32; off; off >>= 1) sum += __shfl_xor(sum, off);
    if (lid == 0) red2[wid] = sum;
    __syncthreads();
    sum = red2[0] + red2[1] + red2[2] + red2[3];
    const float inv = 1.0f / sum;

    union { unsigned short u[8]; uint4 q; } o;
#pragma unroll
    for (int k = 0; k < 8; k++) o.u[k] = f2bf(v[k] * inv);
    *(uint4*)(p + base) = o.q;
}

// ---------- launch ----------
extern "C" void kernel_launch(void* const* d_in, const int* in_sizes, int n_in,
                              void* d_out, int out_size, void* d_ws, size_t ws_size,
                              hipStream_t stream)
{
    const int B = 4, T = 2048, C = 1024, D = 1024;
    const float* x  = (const float*)d_in[0];
    const float* Wq = (const float*)d_in[1];
    const float* Wk = (const float*)d_in[2];
    const float* Wv = (const float*)d_in[3];
    float* out = (float*)d_out;
    char* ws = (char*)d_ws;

    const size_t MB = 1ull << 20;
    // layout (peak 134 MB):
    //   0..16   Xbf          [dead after QKV gemm]
    //  16..22   WqkvT        [dead after QKV gemm]
    //  22..54   QK  (4 x 2048 x 2048 bf16: Q cols 0..1023, K cols 1024..2047)
    //  54..70   Vt  (4 x 1024 x 2048 bf16, written by QKV epilogue VFOLD)
    //  70..102  Sbf (4 x 2048 x 2048 bf16)
    // 102..118  Opart1 (4 x 1024 x 1024 fp32, PV k>=1024 partials)
    // 118..134  Opart0 (4 x 1024 x 1024 fp32, PV k<1024 partials, rows>=1024)
    //   0..32   P   (4 x 2048 x 2048 bf16) [overlays dead Xbf/WqkvT/QK-head]
    unsigned short* Xbf    = (unsigned short*)(ws + 0);
    unsigned short* WqkvT  = (unsigned short*)(ws + 16 * MB);
    unsigned short* QK     = (unsigned short*)(ws + 22 * MB);
    unsigned short* Vt     = (unsigned short*)(ws + 54 * MB);
    unsigned short* Sbf    = (unsigned short*)(ws + 70 * MB);
    float*          Opart1 = (float*)(ws + 102 * MB);
    float*          Opart0 = (float*)(ws + 118 * MB);
    unsigned short* P      = (unsigned short*)(ws + 0);

    const long long sX  = (long long)T * C;        // 2048*1024
    const long long sQK = (long long)T * 2 * D;    // 2048*2048
    const long long sVt = (long long)D * T;        // 1024*2048
    const long long sS  = (long long)T * T;        // 2048*2048
    const long long sO  = (long long)T * D;        // 2048*1024
    const long long sP2 = (long long)1024 * 1024;  // Opart per batch

    // 1) x -> bf16
    {
        int n4 = B * T * C / 4;
        cast_f32_bf16<<<dim3((n4 + 255) / 256), dim3(256), 0, stream>>>(
            (const float4*)x, Xbf, n4);
    }
    // 2) fused W^T cast
    {
        dim3 g(32, 32, 3), b(32, 8);
        transpose_cast_w3<<<g, b, 0, stream>>>(Wq, Wk, Wv, WqkvT, 1024);
    }
    // 3) fused QKV GEMM: Q,K -> QK (ldc 2048); V third -> Vt transposed (VFOLD)
    {
        dim3 g(3072 / 128, 2048 / 128, 4), b(256);
        gemm_bt<unsigned short, false, true, false><<<g, b, 0, stream>>>(
            Xbf, WqkvT, QK, Vt, nullptr, nullptr, 2048, 3072, 1024, 1024, 1024, 2048,
            /*ldvt*/ T, /*nsplit*/ 2048, sX, 0, sQK, sVt, 0, 1.0f);
    }
    // 4) S = Q K^T / 32 -> bf16, causal lower blocks only
    {
        dim3 g(2048 / 128, 2048 / 128, 4), b(256);
        gemm_bt<unsigned short, true, false, false><<<g, b, 0, stream>>>(
            QK, QK + D, Sbf, nullptr, nullptr, nullptr, 2048, 2048, 1024, 2 * D, 2 * D, 2048,
            0, 0, sQK, sQK, sS, 0, 0, 0.03125f);
    }
    // 5) causal softmax (bf16 -> bf16)
    {
        causal_softmax_bf16<<<dim3(B * T), dim3(256), 0, stream>>>(Sbf, P, T);
    }
    // 6) O = P V, split-K at 1024 (heavy chunks first):
    //    rows<1024 -> out; rows>=1024 chunk0 -> Opart0, chunk1 -> Opart1
    {
        dim3 g(1024 / 128, 24, 4), b(256);
        gemm_bt<float, false, false, true><<<g, b, 0, stream>>>(
            P, Vt, out, nullptr, Opart0, Opart1, 2048, 1024, 2048, 2048, 2048, 1024,
            0, 0, sS, sVt, sO, 0, sP2, 1.0f);
    }
    // 7) out rows 1024..2047 = Opart0 + Opart1 (pure write)
    {
        merge_part<<<dim3(4096), dim3(256), 0, stream>>>(out, Opart0, Opart1);
    }
    (void)in_sizes; (void)n_in; (void)out_size; (void)ws_size;
}